// Round 14
// baseline (642.253 us; speedup 1.0000x reference)
//
#include <hip/hip_runtime.h>
#include <math.h>

#define NEG_SLOPE 0.2f

typedef unsigned short u16;
typedef unsigned int u32;
typedef __attribute__((ext_vector_type(8))) short bf16x8;
typedef __attribute__((ext_vector_type(8))) _Float16 f16x8;
typedef __attribute__((ext_vector_type(2))) _Float16 f16x2;
typedef __attribute__((ext_vector_type(4))) float f32x4;

__device__ __forceinline__ float wave_sum(float v){
  #pragma unroll
  for (int o = 1; o < 64; o <<= 1) v += __shfl_xor(v, o, 64);
  return v;
}

__device__ __forceinline__ u16 f2bf(float f){
  u32 u = __float_as_uint(f);
  return (u16)((u + 0x7FFF + ((u >> 16) & 1)) >> 16);
}
__device__ __forceinline__ float bf2f(u16 h){
  return __uint_as_float(((u32)h) << 16);
}

__device__ __forceinline__ void gl_lds16(const void* g, void* l){
  __builtin_amdgcn_global_load_lds((const __attribute__((address_space(1))) u32*)g,
                                   (__attribute__((address_space(3))) u32*)l, 16, 0, 0);
}

// bijective XCD-chunked swizzle (m204)
__device__ __forceinline__ int xcd_swz(int lin, int nwg){
  int xcd = lin & 7;
  int q = nwg >> 3, r = nwg & 7;
  int base = (xcd < r) ? xcd*(q + 1) : r*(q + 1) + (xcd - r)*q;
  return base + (lin >> 3);
}

// alpha contribution of 8 channels: dot(leaky(v + xr + w*we), att) in packed f16
__device__ __forceinline__ float alpha8(f16x8 hv, f16x8 xrh, _Float16 wh, f16x8 weh, f16x8 ath){
  f16x8 tv = hv + xrh + weh*wh;
  f16x8 zero = {0,0,0,0,0,0,0,0};
  f16x8 pos = __builtin_elementwise_max(tv, zero);
  f16x8 neg = __builtin_elementwise_min(tv, zero);
  f16x8 lk  = pos + neg*(_Float16)NEG_SLOPE;
  float p = 0.f;
#if __has_builtin(__builtin_amdgcn_fdot2)
  #pragma unroll
  for (int i = 0; i < 4; i++){
    f16x2 a = {lk[2*i], lk[2*i+1]};
    f16x2 b = {ath[2*i], ath[2*i+1]};
    p = __builtin_amdgcn_fdot2(a, b, p, false);
  }
#else
  #pragma unroll
  for (int j = 0; j < 8; j++) p += (float)lk[j]*(float)ath[j];
#endif
  return p;
}

// ---------------- fused: degree histogram (dst) + edge-weight sum ----------------
__global__ void k_prep(const int* __restrict__ dst, const float* __restrict__ ew, int E,
                       int* __restrict__ deg, float* __restrict__ sum_ew){
  float s = 0.f;
  for (int i = blockIdx.x*blockDim.x + threadIdx.x; i < E; i += gridDim.x*blockDim.x){
    atomicAdd(&deg[dst[i]], 1);
    s += ew[i];
  }
  s = wave_sum(s);
  __shared__ float red[4];
  int lane = threadIdx.x & 63, wid = threadIdx.x >> 6;
  if (lane == 0) red[wid] = s;
  __syncthreads();
  if (threadIdx.x == 0){
    float t = 0.f;
    for (int i = 0; i < (int)(blockDim.x >> 6); i++) t += red[i];
    atomicAdd(sum_ew, t);
  }
}

// ---------------- exclusive scan over N nodes (deg+1 each: self loops) ----------------
__global__ __launch_bounds__(1024) void k_scan(const int* __restrict__ deg, int* __restrict__ rowptr,
                                               int* __restrict__ cursor, int n){
  __shared__ int sums[1024];
  int t = threadIdx.x;
  int CH = (n + 1023) >> 10;
  int base = t*CH;
  int local = 0;
  for (int i = 0; i < CH; i++){ int idx = base + i; if (idx < n) local += deg[idx] + 1; }
  sums[t] = local;
  __syncthreads();
  for (int off = 1; off < 1024; off <<= 1){
    int v = (t >= off) ? sums[t-off] : 0;
    __syncthreads();
    sums[t] += v;
    __syncthreads();
  }
  int run = sums[t] - local;   // exclusive prefix
  for (int i = 0; i < CH; i++){
    int idx = base + i;
    if (idx < n){ rowptr[idx] = run; cursor[idx] = run; run += deg[idx] + 1; }
  }
  if (t == 0) rowptr[n] = sums[1023];
}

// ---------------- scatter edges (+ self loops) into CSR ----------------
__global__ void k_scatter(const int* __restrict__ ei, const float* __restrict__ ew, int E, int n,
                          const float* __restrict__ sum_ew, int* __restrict__ cursor,
                          int* __restrict__ csr_src, float* __restrict__ csr_w){
  int i = blockIdx.x*blockDim.x + threadIdx.x;
  if (i >= E + n) return;
  if (i < E){
    int s = ei[i];         // row 0 = src
    int d = ei[E + i];     // row 1 = dst
    int pos = atomicAdd(&cursor[d], 1);
    csr_src[pos] = s; csr_w[pos] = ew[i];
  } else {
    int v = i - E;
    int pos = atomicAdd(&cursor[v], 1);
    csr_src[pos] = v; csr_w[pos] = (*sum_ew) / (float)E;
  }
}

// ---------------- all 4 weight planes f32->bf16 in one kernel ----------------
__global__ void k_splitW(const float* __restrict__ Wl2, const float* __restrict__ Wr2,
                         const float* __restrict__ Wl3, const float* __restrict__ Wr3,
                         u16* __restrict__ W2lh, u16* __restrict__ W2rh,
                         u16* __restrict__ W3lh, u16* __restrict__ W3rh){
  int i = blockIdx.x*blockDim.x + threadIdx.x;       // grid covers 655360
  if (i < 262144)      W2lh[i]          = f2bf(Wl2[i]);
  else if (i < 524288) W2rh[i - 262144] = f2bf(Wr2[i - 262144]);
  else if (i < 589824) W3lh[i - 524288] = f2bf(Wl3[i - 524288]);
  else if (i < 655360) W3rh[i - 589824] = f2bf(Wr3[i - 589824]);
}

// ---------------- layer-1 linear: x(Nx16) -> xl,xr (Nx512) f16 ----------------
__global__ __launch_bounds__(256) void k_lin1(const float* __restrict__ x,
        const float* __restrict__ Wl, const float* __restrict__ bl,
        const float* __restrict__ Wr, const float* __restrict__ br,
        _Float16* __restrict__ xl, _Float16* __restrict__ xr, int n){
  __shared__ float Ws[16][1028];   // transposed, padded
  __shared__ float bs[1024];
  __shared__ float xs[32][16];
  int t = threadIdx.x;
  for (int i = t; i < 512*16; i += 256){
    int j = i >> 4, k = i & 15;
    Ws[k][j] = Wl[i];
    Ws[k][512 + j] = Wr[i];
  }
  for (int i = t; i < 512; i += 256){ bs[i] = bl[i]; bs[512 + i] = br[i]; }
  int n0 = blockIdx.x * 32;
  for (int i = t; i < 32*16; i += 256){ int r = i >> 4, k = i & 15; xs[r][k] = x[(size_t)(n0 + r)*16 + k]; }
  __syncthreads();
  for (int idx = t; idx < 32*1024; idx += 256){
    int r = idx >> 10, c = idx & 1023;
    float s = bs[c];
    #pragma unroll
    for (int k = 0; k < 16; k++) s += xs[r][k] * Ws[k][c];
    int nn = n0 + r;
    if (c < 512) xl[(size_t)nn*512 + c] = (_Float16)s;
    else         xr[(size_t)nn*512 + (c - 512)] = (_Float16)s;
  }
}

// ---------------- bf16 x bf16 MFMA GEMM (1 term), fused Wl+Wr, XCD-swizzled ----------------
__global__ __launch_bounds__(256,6) void k_gemm_mfma(
    const u16* __restrict__ Ah,
    const u16* __restrict__ Wlh, const u16* __restrict__ Wrh,
    const float* __restrict__ biasl, const float* __restrict__ biasr,
    _Float16* __restrict__ outl, _Float16* __restrict__ outr,
    int n, int K, int J){
  __shared__ __align__(16) u16 lds[8192];   // 16KB: A, W planes of 4096 u16
  u16* lA = lds;
  u16* lW = lds + 4096;
  int t = threadIdx.x;
  int lane = t & 63, w = t >> 6;
  int lane15 = lane & 15, lgrp = lane >> 4;

  int nwg = gridDim.x * gridDim.y;
  int lin = blockIdx.y * gridDim.x + blockIdx.x;
  int swz = xcd_swz(lin, nwg);
  int bx = swz % gridDim.x;            // column/side block (fast within chunk)
  int by = swz / gridDim.x;            // row panel

  int jb = J >> 7;
  int side = bx / jb;
  int j0 = (bx - side*jb) * 128;
  const u16* Wh = side ? Wrh : Wlh;
  const float* bias = side ? biasr : biasl;
  _Float16* out = side ? outr : outl;
  int n0 = by * 128;
  int wm = (w >> 1) * 64, wn = (w & 1) * 64;
  f32x4 acc[4][4] = {};

  int s0 = t, s1 = t + 256;
  int r0 = s0 >> 2, r1 = s1 >> 2;
  int sl0 = (s0 & 3) ^ ((r0 >> 1) & 3);
  int sl1 = (s1 & 3) ^ ((r1 >> 1) & 3);
  size_t arow0 = (size_t)min(n0 + r0, n - 1) * K + sl0*8;
  size_t arow1 = (size_t)min(n0 + r1, n - 1) * K + sl1*8;
  size_t wrow0 = (size_t)(j0 + r0) * K + sl0*8;
  size_t wrow1 = (size_t)(j0 + r1) * K + sl1*8;

  int rcol = (lgrp * 16) ^ (((lane15 >> 1) & 3) << 4);

  for (int k0 = 0; k0 < K; k0 += 32){
    gl_lds16(Ah + arow0 + k0, lA + s0*8);
    gl_lds16(Ah + arow1 + k0, lA + s1*8);
    gl_lds16(Wh + wrow0 + k0, lW + s0*8);
    gl_lds16(Wh + wrow1 + k0, lW + s1*8);
    __syncthreads();
    bf16x8 ah[4], bh[4];
    #pragma unroll
    for (int i = 0; i < 4; i++){
      int qa = (wm + i*16 + lane15)*64 + rcol;
      ah[i]  = *(const bf16x8*)((const char*)lA + qa);
      int qb = (wn + i*16 + lane15)*64 + rcol;
      bh[i]  = *(const bf16x8*)((const char*)lW + qb);
    }
    #pragma unroll
    for (int mi = 0; mi < 4; mi++)
      #pragma unroll
      for (int ni = 0; ni < 4; ni++)
        acc[mi][ni] = __builtin_amdgcn_mfma_f32_16x16x32_bf16(ah[mi], bh[ni], acc[mi][ni], 0, 0, 0);
    __syncthreads();
  }

  #pragma unroll
  for (int ni = 0; ni < 4; ni++){
    int col = j0 + wn + ni*16 + lane15;
    float bia = bias[col];
    #pragma unroll
    for (int mi = 0; mi < 4; mi++){
      int rowb = n0 + wm + mi*16 + lgrp*4;
      #pragma unroll
      for (int rg = 0; rg < 4; rg++){
        int row = rowb + rg;
        if (row < n) out[(size_t)row*J + col] = (_Float16)(acc[mi][ni][rg] + bia);
      }
    }
  }
}

// ---------------- GATv2 4-head agg + bias + LayerNorm + ELU, emit bf16 ----------------
// ONE WAVE per node: lane owns channels (lane>>4)*128 + (lane&15)*8; the 4
// 16-lane groups are the 4 heads processing the SAME edge list in lockstep.
// No cross-group merge, LN = in-wave butterfly, zero barriers/LDS.
__global__ __launch_bounds__(128) void k_agg4(
                      const _Float16* __restrict__ xl, const _Float16* __restrict__ xr,
                      const float* __restrict__ We, const float* __restrict__ att, const float* __restrict__ bo,
                      const float* __restrict__ gam, const float* __restrict__ bet,
                      const int* __restrict__ rowptr, const int* __restrict__ csr_src,
                      const float* __restrict__ csr_w,
                      u16* __restrict__ oh, int n){
  constexpr int HC_ = 512;
  constexpr float RT = 8.f;
  constexpr int NB = 2;
  int t = threadIdx.x;
  int widx = t >> 6, lane = t & 63;
  int l16 = lane & 15, grp = lane >> 4;    // grp = head
  int c0 = grp*128 + l16*8;                // 8 channels per lane, unique per lane

  // edge-phase params in f16 only
  float4 wea = *(const float4*)&We[c0],  web = *(const float4*)&We[c0 + 4];
  float4 ata = *(const float4*)&att[c0], atb = *(const float4*)&att[c0 + 4];
  f16x8 weh, ath;
  #pragma unroll
  for (int j = 0; j < 4; j++){
    weh[j] = (_Float16)((&wea.x)[j]); weh[4+j] = (_Float16)((&web.x)[j]);
    ath[j] = (_Float16)((&ata.x)[j]); ath[4+j] = (_Float16)((&atb.x)[j]);
  }

  #pragma unroll 1
  for (int ib = 0; ib < NB; ib++){
    int nid = blockIdx.x*(2*NB) + widx*NB + ib;
    if (nid >= n) continue;                // wave-uniform; no barriers anywhere

    f16x8 xrh = *(const f16x8*)(xr + (size_t)nid*HC_ + c0);
    int rs = __builtin_amdgcn_readfirstlane(rowptr[nid]);
    int re = __builtin_amdgcn_readfirstlane(rowptr[nid + 1]);

    float m = -3e38f, d = 0.f;
    float acc[8] = {};
    for (int e0 = rs; e0 < re; e0 += 2){
      int e1 = e0 + 1;
      bool has1 = e1 < re;
      int s0 = csr_src[e0];
      int s1 = has1 ? csr_src[e1] : s0;
      float w0 = csr_w[e0];
      float w1 = has1 ? csr_w[e1] : 0.f;
      f16x8 hv0 = *(const f16x8*)(xl + (size_t)s0*HC_ + c0);
      f16x8 hv1 = *(const f16x8*)(xl + (size_t)s1*HC_ + c0);
      float p0 = alpha8(hv0, xrh, (_Float16)w0, weh, ath);
      float p1 = alpha8(hv1, xrh, (_Float16)w1, weh, ath);
      #pragma unroll
      for (int o = 1; o < 16; o <<= 1){    // reduce within 16-lane head group
        p0 += __shfl_xor(p0, o, 64);
        p1 += __shfl_xor(p1, o, 64);
      }
      if (!has1) p1 = -3e38f;
      float pm = fmaxf(p0, p1);
      if (pm > m + RT){                    // rare rescale (defer-max)
        float sc = __expf(m - pm);
        d *= sc;
        #pragma unroll
        for (int j = 0; j < 8; j++) acc[j] *= sc;
        m = pm;
      }
      float e0x = __expf(p0 - m), e1x = __expf(p1 - m);
      d += e0x + e1x;
      float v0[8], v1[8];
      #pragma unroll
      for (int j = 0; j < 8; j++){ v0[j] = (float)hv0[j]; v1[j] = (float)hv1[j]; }
      #pragma unroll
      for (int j = 0; j < 8; j++) acc[j] += e0x*v0[j] + e1x*v1[j];
    }
    float inv = 1.f / (d + 1e-16f);
    float4 boa = *(const float4*)&bo[c0], bob = *(const float4*)&bo[c0 + 4];
    float o8[8];
    #pragma unroll
    for (int j = 0; j < 4; j++){
      o8[j]   = acc[j]*inv   + (&boa.x)[j];
      o8[4+j] = acc[4+j]*inv + (&bob.x)[j];
    }

    // LayerNorm over all 512 channels: in-wave 6-step butterfly
    float s1 = 0.f, s2 = 0.f;
    #pragma unroll
    for (int j = 0; j < 8; j++){ s1 += o8[j]; s2 += o8[j]*o8[j]; }
    #pragma unroll
    for (int o = 1; o < 64; o <<= 1){ s1 += __shfl_xor(s1, o, 64); s2 += __shfl_xor(s2, o, 64); }
    float mu = s1 / (float)HC_;
    float var = s2 / (float)HC_ - mu*mu;
    float rstd = rsqrtf(var + 1e-5f);
    float4 ga = *(const float4*)&gam[c0], gb = *(const float4*)&gam[c0 + 4];
    float4 ba = *(const float4*)&bet[c0], bb = *(const float4*)&bet[c0 + 4];
    float y[8];
    #pragma unroll
    for (int j = 0; j < 4; j++){
      float ya = (o8[j]   - mu)*rstd*(&ga.x)[j] + (&ba.x)[j];
      float yb = (o8[4+j] - mu)*rstd*(&gb.x)[j] + (&bb.x)[j];
      y[j]   = (ya > 0.f) ? ya : (__expf(ya) - 1.f);   // ELU
      y[4+j] = (yb > 0.f) ? yb : (__expf(yb) - 1.f);
    }
    // every lane writes its own 8 channels as bf16 (16B)
    u32 hv2[4];
    #pragma unroll
    for (int j = 0; j < 4; j++){
      u16 h0 = f2bf(y[2*j]), h1 = f2bf(y[2*j+1]);
      hv2[j] = (u32)h0 | ((u32)h1 << 16);
    }
    *(uint4*)&oh[(size_t)nid*HC_ + c0] = make_uint4(hv2[0],hv2[1],hv2[2],hv2[3]);
  }
}

// ---------------- layer-3 agg (1 head, no ELU, f32 out): one node per 16-lane group ----------------
__global__ __launch_bounds__(64) void k_agg1(
                      const _Float16* __restrict__ xl, const _Float16* __restrict__ xr,
                      const float* __restrict__ We, const float* __restrict__ att, const float* __restrict__ bo,
                      const float* __restrict__ gam, const float* __restrict__ bet,
                      const int* __restrict__ rowptr, const int* __restrict__ csr_src,
                      const float* __restrict__ csr_w,
                      float* __restrict__ out, int n){
  constexpr float RT = 8.f;
  int lane = threadIdx.x;
  int l16 = lane & 15, grp = lane >> 4;
  int c0 = l16*8;

  float4 wea = *(const float4*)&We[c0],  web = *(const float4*)&We[c0 + 4];
  float4 ata = *(const float4*)&att[c0], atb = *(const float4*)&att[c0 + 4];
  float4 boa = *(const float4*)&bo[c0],  bob = *(const float4*)&bo[c0 + 4];
  float4 ga  = *(const float4*)&gam[c0], gb  = *(const float4*)&gam[c0 + 4];
  float4 ba  = *(const float4*)&bet[c0], bb  = *(const float4*)&bet[c0 + 4];
  float bo8[8] = {boa.x,boa.y,boa.z,boa.w,bob.x,bob.y,bob.z,bob.w};
  float g8[8]  = {ga.x,ga.y,ga.z,ga.w,gb.x,gb.y,gb.z,gb.w};
  float b8[8]  = {ba.x,ba.y,ba.z,ba.w,bb.x,bb.y,bb.z,bb.w};
  f16x8 weh, ath;
  #pragma unroll
  for (int j = 0; j < 4; j++){
    weh[j] = (_Float16)((&wea.x)[j]); weh[4+j] = (_Float16)((&web.x)[j]);
    ath[j] = (_Float16)((&ata.x)[j]); ath[4+j] = (_Float16)((&atb.x)[j]);
  }

  int nid = blockIdx.x*4 + grp;
  if (nid >= n) return;            // per-group; no barriers below

  f16x8 xrh = *(const f16x8*)(xr + (size_t)nid*128 + c0);
  int rs = rowptr[nid], re = rowptr[nid + 1];
  float m = -3e38f, d = 0.f;
  float acc[8] = {};
  for (int e0 = rs; e0 < re; e0 += 2){
    int e1 = e0 + 1;
    bool has1 = e1 < re;
    int s0 = csr_src[e0];
    int s1 = has1 ? csr_src[e1] : s0;
    float w0 = csr_w[e0];
    float w1 = has1 ? csr_w[e1] : 0.f;
    f16x8 hv0 = *(const f16x8*)(xl + (size_t)s0*128 + c0);
    f16x8 hv1 = *(const f16x8*)(xl + (size_t)s1*128 + c0);
    float p0 = alpha8(hv0, xrh, (_Float16)w0, weh, ath);
    float p1 = alpha8(hv1, xrh, (_Float16)w1, weh, ath);
    #pragma unroll
    for (int o = 1; o < 16; o <<= 1){
      p0 += __shfl_xor(p0, o, 64);
      p1 += __shfl_xor(p1, o, 64);
    }
    if (!has1) p1 = -3e38f;
    float pm = fmaxf(p0, p1);
    if (pm > m + RT){
      float sc = __expf(m - pm);
      d *= sc;
      #pragma unroll
      for (int j = 0; j < 8; j++) acc[j] *= sc;
      m = pm;
    }
    float e0x = __expf(p0 - m), e1x = __expf(p1 - m);
    d += e0x + e1x;
    float v0[8], v1[8];
    #pragma unroll
    for (int j = 0; j < 8; j++){ v0[j] = (float)hv0[j]; v1[j] = (float)hv1[j]; }
    #pragma unroll
    for (int j = 0; j < 8; j++) acc[j] += e0x*v0[j] + e1x*v1[j];
  }
  float inv = 1.f / (d + 1e-16f);
  float o8[8];
  #pragma unroll
  for (int j = 0; j < 8; j++) o8[j] = acc[j]*inv + bo8[j];

  // LayerNorm over 128 channels (group-local)
  float s1 = 0.f, s2 = 0.f;
  #pragma unroll
  for (int j = 0; j < 8; j++){ s1 += o8[j]; s2 += o8[j]*o8[j]; }
  #pragma unroll
  for (int o = 1; o < 16; o <<= 1){ s1 += __shfl_xor(s1, o, 64); s2 += __shfl_xor(s2, o, 64); }
  float mu = s1 / 128.f;
  float var = s2 / 128.f - mu*mu;
  float rstd = rsqrtf(var + 1e-5f);
  float y[8];
  #pragma unroll
  for (int j = 0; j < 8; j++) y[j] = (o8[j] - mu)*rstd*g8[j] + b8[j];
  float* orow = out + (size_t)nid*128 + c0;
  *(float4*)orow       = make_float4(y[0],y[1],y[2],y[3]);
  *(float4*)(orow + 4) = make_float4(y[4],y[5],y[6],y[7]);
}

// ---------------- policy/value heads on one node ----------------
__global__ __launch_bounds__(128) void k_heads(const float* __restrict__ h3, const int* __restrict__ idxp,
        const float* __restrict__ Pw1, const float* __restrict__ Pb1,
        const float* __restrict__ Pw2, const float* __restrict__ Pb2,
        const float* __restrict__ Vw1, const float* __restrict__ Vb1,
        const float* __restrict__ Vw2, const float* __restrict__ Vb2,
        float* __restrict__ out){
  __shared__ float z[128], hp[128], hv[128];
  int t = threadIdx.x;
  int idx = *idxp;
  z[t] = h3[(size_t)idx*128 + t];
  __syncthreads();
  float sp = Pb1[t], sv = Vb1[t];
  for (int c = 0; c < 128; c++){
    float zc = z[c];
    sp += Pw1[t*128 + c] * zc;
    sv += Vw1[t*128 + c] * zc;
  }
  hp[t] = fmaxf(sp, 0.f);
  hv[t] = fmaxf(sv, 0.f);
  __syncthreads();
  if (t < 64){
    float l0 = Pw2[t]*hp[t]       + Pw2[64 + t]*hp[64 + t];
    float l1 = Pw2[128 + t]*hp[t] + Pw2[192 + t]*hp[64 + t];
    float vv = Vw2[t]*hv[t]       + Vw2[64 + t]*hv[64 + t];
    #pragma unroll
    for (int o = 1; o < 64; o <<= 1){
      l0 += __shfl_xor(l0, o, 64); l1 += __shfl_xor(l1, o, 64); vv += __shfl_xor(vv, o, 64);
    }
    if (t == 0){ out[0] = l0 + Pb2[0]; out[1] = l1 + Pb2[1]; out[2] = vv + Vb2[0]; }
  }
}

extern "C" void kernel_launch(void* const* d_in, const int* in_sizes, int n_in,
                              void* d_out, int out_size, void* d_ws, size_t ws_size,
                              hipStream_t stream){
  const float* x    = (const float*)d_in[0];
  const int*   ei   = (const int*)d_in[1];
  const float* ew   = (const float*)d_in[2];
  const int*   nidx = (const int*)d_in[3];
  const float* Wl1 = (const float*)d_in[4];  const float* bl1 = (const float*)d_in[5];
  const float* Wr1 = (const float*)d_in[6];  const float* br1 = (const float*)d_in[7];
  const float* We1 = (const float*)d_in[8];  const float* att1 = (const float*)d_in[9];
  const float* bo1 = (const float*)d_in[10];
  const float* Wl2 = (const float*)d_in[11]; const float* bl2 = (const float*)d_in[12];
  const float* Wr2 = (const float*)d_in[13]; const float* br2 = (const float*)d_in[14];
  const float* We2 = (const float*)d_in[15]; const float* att2 = (const float*)d_in[16];
  const float* bo2 = (const float*)d_in[17];
  const float* Wl3 = (const float*)d_in[18]; const float* bl3 = (const float*)d_in[19];
  const float* Wr3 = (const float*)d_in[20]; const float* br3 = (const float*)d_in[21];
  const float* We3 = (const float*)d_in[22]; const float* att3 = (const float*)d_in[23];
  const float* bo3 = (const float*)d_in[24];
  const float* gn1 = (const float*)d_in[25]; const float* bn1 = (const float*)d_in[26];
  const float* gn2 = (const float*)d_in[27]; const float* bn2 = (const float*)d_in[28];
  const float* gn3 = (const float*)d_in[29]; const float* bn3 = (const float*)d_in[30];
  const float* Pw1 = (const float*)d_in[31]; const float* Pb1 = (const float*)d_in[32];
  const float* Pw2 = (const float*)d_in[33]; const float* Pb2 = (const float*)d_in[34];
  const float* Vw1 = (const float*)d_in[35]; const float* Vb1 = (const float*)d_in[36];
  const float* Vw2 = (const float*)d_in[37]; const float* Vb2 = (const float*)d_in[38];

  const int N = in_sizes[0] / 16;
  const int E = in_sizes[2];
  const int NE = N + E;

  char* w = (char*)d_ws;
  size_t off = 0;
  float* sum_ew = (float*)(w + off); off += 256;
  int* rowptr = (int*)(w + off); off += (size_t)(N + 1)*4; off = (off + 255) & ~(size_t)255;
  int* cursor = (int*)(w + off); off += (size_t)N*4;       off = (off + 255) & ~(size_t)255;
  int* deg    = (int*)(w + off); off += (size_t)N*4;       off = (off + 255) & ~(size_t)255;
  int* csr_src= (int*)(w + off); off += (size_t)NE*4;      off = (off + 255) & ~(size_t)255;
  float* csr_w= (float*)(w + off); off += (size_t)NE*4;    off = (off + 255) & ~(size_t)255;
  // weight bf16 planes (single hi plane each)
  u16* W2lh = (u16*)(w + off); off += (size_t)512*512*2;
  u16* W2rh = (u16*)(w + off); off += (size_t)512*512*2;
  u16* W3lh = (u16*)(w + off); off += (size_t)128*512*2;
  u16* W3rh = (u16*)(w + off); off += (size_t)128*512*2;
  off = (off + 1048575) & ~(size_t)1048575;   // 1MB align for big buffers
  _Float16* A  = (_Float16*)(w + off); off += (size_t)N*512*2;
  _Float16* B  = (_Float16*)(w + off); off += (size_t)N*512*2;
  u16*   Ch = (u16*)(w + off);   off += (size_t)N*512*2;
  float* D  = (float*)(w + off); off += (size_t)N*128*4;
  (void)ws_size; (void)n_in; (void)out_size;

  hipMemsetAsync(sum_ew, 0, 4, stream);
  hipMemsetAsync(deg, 0, (size_t)N*4, stream);

  k_prep<<<256, 256, 0, stream>>>(ei + E, ew, E, deg, sum_ew);
  k_scan<<<1, 1024, 0, stream>>>(deg, rowptr, cursor, N);
  k_scatter<<<(NE + 255)/256, 256, 0, stream>>>(ei, ew, E, N, sum_ew, cursor, csr_src, csr_w);
  k_splitW<<<2560, 256, 0, stream>>>(Wl2, Wr2, Wl3, Wr3, W2lh, W2rh, W3lh, W3rh);

  const int GY = (N + 127)/128;

  // Layer 1
  k_lin1<<<N/32, 256, 0, stream>>>(x, Wl1, bl1, Wr1, br1, A, B, N);
  k_agg4<<<(N + 3)/4, 128, 0, stream>>>(A, B, We1, att1, bo1, gn1, bn1,
                                        rowptr, csr_src, csr_w, Ch, N);
  // Layer 2 (fused Wl+Wr dispatch, bf16 A)
  k_gemm_mfma<<<dim3(8, GY), 256, 0, stream>>>(Ch, W2lh, W2rh, bl2, br2, A, B, N, 512, 512);
  k_agg4<<<(N + 3)/4, 128, 0, stream>>>(A, B, We2, att2, bo2, gn2, bn2,
                                        rowptr, csr_src, csr_w, Ch, N);
  // Layer 3 (fused)
  k_gemm_mfma<<<dim3(2, GY), 256, 0, stream>>>(Ch, W3lh, W3rh, bl3, br3, A, B, N, 512, 128);
  k_agg1<<<(N + 3)/4, 64, 0, stream>>>(A, B, We3, att3, bo3, gn3, bn3,
                                       rowptr, csr_src, csr_w, D, N);
  // Heads
  k_heads<<<1, 128, 0, stream>>>(D, nidx, Pw1, Pb1, Pw2, Pb2, Vw1, Vb1, Vw2, Vb2, (float*)d_out);
}